// Round 18
// baseline (156.234 us; speedup 1.0000x reference)
//
#include <hip/hip_runtime.h>

#define B_ 4096
#define D_ 256
#define N_ 8192
// log2(e)/0.07
#define EXP2SC 20.60992915555662f

typedef float f32x4 __attribute__((ext_vector_type(4)));
typedef __bf16 bf16x8 __attribute__((ext_vector_type(8)));

__device__ __forceinline__ float fast_exp2(float x){
#if __has_builtin(__builtin_amdgcn_exp2f)
  return __builtin_amdgcn_exp2f(x);
#else
  return exp2f(x);
#endif
}

__device__ __forceinline__ unsigned short f2bf(float x){
  unsigned int u = __float_as_uint(x);
  unsigned int r = (u + 0x7fffu + ((u >> 16) & 1u)) >> 16;
  return (unsigned short)r;
}

// --- kernel A: pack labels + zero accumulators + zero done-counter ---
__global__ __launch_bounds__(256) void pack_kernel(const float* __restrict__ labels,
                                                   ulonglong2* __restrict__ bits,
                                                   int* __restrict__ scnt,
                                                   float* __restrict__ possum,
                                                   float* __restrict__ total,
                                                   int* __restrict__ poscnt,
                                                   unsigned int* __restrict__ done){
  int i = blockIdx.x * 256 + threadIdx.x;      // 0..4095
  if (i == 0) *done = 0u;
  possum[i] = 0.f; total[i] = 0.f; poscnt[i] = 0;
  const float* L = labels + (size_t)i * 80;
  unsigned long long lo = 0ull, hi = 0ull;
  #pragma unroll
  for (int c = 0; c < 64; ++c) lo |= (L[c] > 0.5f) ? (1ull << c) : 0ull;
  #pragma unroll
  for (int c = 64; c < 80; ++c) hi |= (L[c] > 0.5f) ? (1ull << (c - 64)) : 0ull;
  bits[i] = make_ulonglong2(lo, hi);
  scnt[i] = __popcll(lo) + __popcll(hi);
}

// --- kernel B: conv (blocks 0..1023) || pos (blocks 1024..5119), independent ---
// conv: r17-verified inverted fragment-major mapping (wave writes 1KB linear).
// pos:  r17-verified Jaccard bitmask + fused per-row popcount.
__global__ __launch_bounds__(256) void convpos_kernel(const float* __restrict__ f,
                                                      unsigned short* __restrict__ ctr,
                                                      const ulonglong2* __restrict__ bits,
                                                      const int* __restrict__ scnt,
                                                      unsigned long long* __restrict__ posw,
                                                      int* __restrict__ poscnt){
  int bid = blockIdx.x;
  int tid = threadIdx.x;
  if (bid < 1024){
    int t = bid * 256 + tid;                   // 0..262143, one 16B unit each
    int l  = t & 63;
    int fg = t >> 9;                           // fragment group 0..511
    int cg = (t >> 6) & 7;                     // chunk group 0..7
    int j  = l >> 4;                           // chunk-in-group 0..3
    int r  = l & 15;                           // row-in-group 0..15
    int row = (fg << 4) + r;                   // 0..8191
    int c   = (cg << 2) + j;                   // 16B chunk 0..31
    int v = row >> 12, b = row & 4095;
    const float* src = f + ((((size_t)b << 1) + v) << 8) + (c << 3);
    float4 a = *(const float4*)src;
    float4 cc = *(const float4*)(src + 4);
    uint4 o;
    o.x = (unsigned)f2bf(a.x)  | ((unsigned)f2bf(a.y)  << 16);
    o.y = (unsigned)f2bf(a.z)  | ((unsigned)f2bf(a.w)  << 16);
    o.z = (unsigned)f2bf(cc.x) | ((unsigned)f2bf(cc.y) << 16);
    o.w = (unsigned)f2bf(cc.z) | ((unsigned)f2bf(cc.w) << 16);
    *(uint4*)((char*)ctr + ((size_t)t << 4)) = o;
  } else {
    __shared__ unsigned long long rbl[16], rbh[16];
    __shared__ int rs_sh[16];
    int pb = bid - 1024;                       // 0..4095
    int i0 = (pb >> 4) << 4;                   // row group base
    int jm = ((pb & 15) << 8) + tid;           // this thread's column
    if (tid < 16){
      ulonglong2 bb = bits[i0 + tid];
      rbl[tid] = bb.x; rbh[tid] = bb.y;
      rs_sh[tid] = scnt[i0 + tid];
    }
    __syncthreads();
    ulonglong2 bj = bits[jm];
    int sj = scnt[jm];
    int lane = tid & 63;
    int wword = ((pb & 15) << 2) + (tid >> 6); // jm >> 6
    #pragma unroll
    for (int r = 0; r < 16; ++r){
      int inter = __popcll(rbl[r] & bj.x) + __popcll(rbh[r] & bj.y);
      int uni = rs_sh[r] + sj - inter;
      bool hit = false;
      if (2 * inter >= uni){                   // integer prefilter (superset)
        float sim = (float)inter / ((float)uni + 1e-6f);
        hit = (sim >= 0.5f);
      }
      unsigned long long m = __ballot(hit);
      if (lane == 0){
        posw[(size_t)(i0 + r) * 64 + wword] = m;
        if (m) atomicAdd(&poscnt[i0 + r], __popcll(m));
      }
    }
  }
}

// ---- kernel C: fused GEMM (r17-exact) + last-block finalize ----
#define GLDS16(g, l) __builtin_amdgcn_global_load_lds( \
    (const __attribute__((address_space(1))) unsigned int*)(unsigned long long)(uintptr_t)(g), \
    (__attribute__((address_space(3))) unsigned int*)(unsigned int)(uintptr_t)(l), 16, 0, 0)

__global__ __launch_bounds__(256) void gemm_kernel(const unsigned short* __restrict__ ctr,
                                                   const unsigned long long* __restrict__ posw,
                                                   float* __restrict__ total,
                                                   float* __restrict__ possum,
                                                   const int* __restrict__ poscnt,
                                                   const int* __restrict__ scnt,
                                                   unsigned int* __restrict__ done,
                                                   float* __restrict__ out){
  __shared__ __align__(16) char Bl[32768];     // 4 col-groups x 8KB, fm order
  const int tid  = threadIdx.x;
  const int lane = tid & 63;
  const int w    = tid >> 6;                   // 0..3
  const int lr   = lane & 15, lk = lane >> 4;
  const int bid = (int)blockIdx.x;

  int rb, cb;
  bool doCol;
  if (bid < 1024){
    const int swz = (bid & 7) * 128 + (bid >> 3);
    rb = swz & 31; cb = 32 + (swz >> 5);
    doCol = false;
  } else {
    int t0 = bid - 1024;                       // 0..527
    int t  = (t0 & 7) * 66 + (t0 >> 3);
    int r = (int)((65.0f - sqrtf((float)(4225 - 8 * t))) * 0.5f);
    while ((r + 1) * (65 - (r + 1)) / 2 <= t) ++r;
    while (r * (65 - r) / 2 > t) --r;
    rb = r;
    cb = r + (t - r * (65 - r) / 2);
    doCol = (rb != cb);
  }
  const int i0 = rb << 7, n0 = cb << 7;
  const char* ctrB = (const char*)ctr;

  #define STAGEH(H) do { \
    const char* src_ = ctrB + ((size_t)((n0 >> 4) + ((H) << 2)) << 13); \
    _Pragma("unroll") \
    for (int is = 0; is < 8; ++is){ \
      int off_ = (is << 12) + (w << 10);       /* wave-uniform */ \
      GLDS16(src_ + off_ + (lane << 4), Bl + off_); \
    } } while(0)

  // ---- A fragments: contiguous 1KB per wave-load (fragment-major)
  bf16x8 a[2][8];
  #pragma unroll
  for (int rt = 0; rt < 2; ++rt){
    const char* gbase = ctrB + ((size_t)((i0 >> 4) + (w << 1) + rt) << 13);
    #pragma unroll
    for (int ks = 0; ks < 8; ++ks)
      a[rt][ks] = *(const bf16x8*)(gbase + (ks << 10) + (lane << 4));
  }

  const int rowb = i0 + (w << 5) + (lk << 2);  // + rt*16 + q = this lane's rows
  float tot[2][4], pos[2][4];
  #pragma unroll
  for (int rt = 0; rt < 2; ++rt)
    #pragma unroll
    for (int q = 0; q < 4; ++q){ tot[rt][q] = 0.f; pos[rt][q] = 0.f; }

  STAGEH(0);
  __syncthreads();
  #pragma unroll
  for (int h = 0; h < 2; ++h){
    if (h){
      __syncthreads();                         // all reads of half0 done
      STAGEH(1);
      __syncthreads();
    }
    const int widx = ((n0 & 4095) >> 6) + h;
    unsigned pbits = 0;
    #pragma unroll
    for (int rt = 0; rt < 2; ++rt)
      #pragma unroll
      for (int q = 0; q < 4; ++q){
        unsigned long long wv = posw[(size_t)(rowb + (rt << 4) + q) * 64 + widx];
        unsigned m4 = (unsigned)((wv >> lr) & 1ull)
                    | ((unsigned)((wv >> (16 + lr)) & 1ull) << 1)
                    | ((unsigned)((wv >> (32 + lr)) & 1ull) << 2)
                    | ((unsigned)((wv >> (48 + lr)) & 1ull) << 3);
        pbits |= m4 << (((rt << 2) + q) << 2);
      }

    #pragma unroll
    for (int ng = 0; ng < 4; ++ng){
      const char* bbase = Bl + (ng << 13);     // 8KB per col-group
      f32x4 acc0 = {0.f, 0.f, 0.f, 0.f};
      f32x4 acc1 = {0.f, 0.f, 0.f, 0.f};
      #pragma unroll
      for (int ks = 0; ks < 8; ++ks){
        bf16x8 b = *(const bf16x8*)(bbase + (ks << 10) + (lane << 4));
        acc0 = __builtin_amdgcn_mfma_f32_16x16x32_bf16(a[0][ks], b, acc0, 0, 0, 0);
        acc1 = __builtin_amdgcn_mfma_f32_16x16x32_bf16(a[1][ks], b, acc1, 0, 0, 0);
      }
      const int gcol = n0 + (h << 6) + (ng << 4) + lr;
      float ct = 0.f, cp = 0.f;                // column partials (this lane)
      #pragma unroll
      for (int q = 0; q < 4; ++q){
        float e0 = fast_exp2(acc0[q] * EXP2SC);
        e0 = ((rowb + q) == gcol) ? 0.f : e0;
        tot[0][q] += e0;
        bool b0 = (pbits >> ((q << 2) + ng)) & 1u;
        if (b0) pos[0][q] += e0;
        float e1 = fast_exp2(acc1[q] * EXP2SC);
        e1 = ((rowb + 16 + q) == gcol) ? 0.f : e1;
        tot[1][q] += e1;
        bool b1 = (pbits >> (((4 + q) << 2) + ng)) & 1u;
        if (b1) pos[1][q] += e1;
        if (doCol){
          ct += e0 + e1;
          cp += (b0 ? e0 : 0.f) + (b1 ? e1 : 0.f);
        }
      }
      if (doCol){
        ct += __shfl_xor(ct, 16); cp += __shfl_xor(cp, 16);
        ct += __shfl_xor(ct, 32); cp += __shfl_xor(cp, 32);
        if (lk == 0){                          // one lane per column per wave
          atomicAdd(&total[gcol], ct);
          if (cp != 0.f) atomicAdd(&possum[gcol], cp);
        }
      }
    }
  }

  // ---- reduce across lr (16 lanes) and one atomic pair per row ----
  #pragma unroll
  for (int rt = 0; rt < 2; ++rt){
    #pragma unroll
    for (int q = 0; q < 4; ++q){
      float v = tot[rt][q], u = pos[rt][q];
      v += __shfl_xor(v, 1); u += __shfl_xor(u, 1);
      v += __shfl_xor(v, 2); u += __shfl_xor(u, 2);
      v += __shfl_xor(v, 4); u += __shfl_xor(u, 4);
      v += __shfl_xor(v, 8); u += __shfl_xor(u, 8);
      if (lr == 0){
        int grow = rowb + (rt << 4) + q;
        atomicAdd(&total[grow], v);
        if (u != 0.f) atomicAdd(&possum[grow], u);
      }
    }
  }

  // ---- last-block finalize (replaces fin_kernel launch) ----
  __threadfence();                             // this block's atomics visible
  __shared__ int lastblk;
  __syncthreads();                             // (also drains this block's atomics)
  if (tid == 0) lastblk = (atomicAdd(done, 1u) == 1551u) ? 1 : 0;
  __syncthreads();
  if (lastblk){
    float ls = 0.f, hc = 0.f;
    #pragma unroll
    for (int k = 0; k < 16; ++k){
      int i = (k << 8) + tid;                  // 256 threads x 16 rows
      int pii = (scnt[i] > 0) ? 1 : 0;
      int pm = 2 * poscnt[i] - pii;            // pos_m row count
      if (pm > 0){
        // device-scope atomic reads: coherent vs all blocks' atomicAdds
        float ps = atomicAdd(&possum[i], 0.f);
        float tt = atomicAdd(&total[i], 0.f);
        float neg = tt - ps;
        ls += logf((ps + neg + 1e-8f) / ps);
        hc += 1.f;
      }
    }
    ls += __shfl_xor(ls, 1);  ls += __shfl_xor(ls, 2);  ls += __shfl_xor(ls, 4);
    ls += __shfl_xor(ls, 8);  ls += __shfl_xor(ls, 16); ls += __shfl_xor(ls, 32);
    hc += __shfl_xor(hc, 1);  hc += __shfl_xor(hc, 2);  hc += __shfl_xor(hc, 4);
    hc += __shfl_xor(hc, 8);  hc += __shfl_xor(hc, 16); hc += __shfl_xor(hc, 32);
    __shared__ float sl[4], sh[4];
    if ((tid & 63) == 0){ sl[tid >> 6] = ls; sh[tid >> 6] = hc; }
    __syncthreads();
    if (tid == 0){
      float S = sl[0] + sl[1] + sl[2] + sl[3];
      float H = sh[0] + sh[1] + sh[2] + sh[3];
      out[0] = S / fmaxf(H, 1.f);
    }
  }
  #undef STAGEH
}

extern "C" void kernel_launch(void* const* d_in, const int* in_sizes, int n_in,
                              void* d_out, int out_size, void* d_ws, size_t ws_size,
                              hipStream_t stream){
  (void)in_sizes; (void)n_in; (void)out_size; (void)ws_size;
  const float* feat   = (const float*)d_in[0];
  const float* labels = (const float*)d_in[1];
  float* out = (float*)d_out;
  char* ws = (char*)d_ws;
  unsigned short* ctr       = (unsigned short*)(ws);               // 4,194,304 B
  unsigned long long* posw  = (unsigned long long*)(ws + 4194304); // 2,097,152 B
  ulonglong2* bits          = (ulonglong2*)(ws + 6291456);         //    65,536 B
  int* scnt                 = (int*)(ws + 6356992);                //    16,384 B
  float* possum             = (float*)(ws + 6373376);              //    16,384 B
  float* total              = (float*)(ws + 6389760);              //    16,384 B
  int* poscnt               = (int*)(ws + 6406144);                //    16,384 B
  unsigned int* done        = (unsigned int*)(ws + 6422528);       //         4 B

  hipLaunchKernelGGL(pack_kernel,    dim3(16),   dim3(256), 0, stream, labels, bits, scnt, possum, total, poscnt, done);
  hipLaunchKernelGGL(convpos_kernel, dim3(5120), dim3(256), 0, stream, feat, ctr, bits, scnt, posw, poscnt);
  hipLaunchKernelGGL(gemm_kernel,    dim3(1552), dim3(256), 0, stream, ctr, posw, total, possum, poscnt, scnt, done, out);
}

// Round 19
// 59.643 us; speedup vs baseline: 2.6195x; 2.6195x over previous
//
#include <hip/hip_runtime.h>

#define B_ 4096
#define D_ 256
#define N_ 8192
// log2(e)/0.07
#define EXP2SC 20.60992915555662f

typedef float f32x4 __attribute__((ext_vector_type(4)));
typedef __bf16 bf16x8 __attribute__((ext_vector_type(8)));

__device__ __forceinline__ float fast_exp2(float x){
#if __has_builtin(__builtin_amdgcn_exp2f)
  return __builtin_amdgcn_exp2f(x);
#else
  return exp2f(x);
#endif
}

__device__ __forceinline__ unsigned short f2bf(float x){
  unsigned int u = __float_as_uint(x);
  unsigned int r = (u + 0x7fffu + ((u >> 16) & 1u)) >> 16;
  return (unsigned short)r;
}

// --- kernel A: pack labels + zero accumulators (r12-verified math) ---
__global__ __launch_bounds__(256) void pack_kernel(const float* __restrict__ labels,
                                                   ulonglong2* __restrict__ bits,
                                                   int* __restrict__ scnt,
                                                   float* __restrict__ possum,
                                                   float* __restrict__ total,
                                                   int* __restrict__ poscnt){
  int i = blockIdx.x * 256 + threadIdx.x;      // 0..4095
  possum[i] = 0.f; total[i] = 0.f; poscnt[i] = 0;
  const float* L = labels + (size_t)i * 80;
  unsigned long long lo = 0ull, hi = 0ull;
  #pragma unroll
  for (int c = 0; c < 64; ++c) lo |= (L[c] > 0.5f) ? (1ull << c) : 0ull;
  #pragma unroll
  for (int c = 64; c < 80; ++c) hi |= (L[c] > 0.5f) ? (1ull << (c - 64)) : 0ull;
  bits[i] = make_ulonglong2(lo, hi);
  scnt[i] = __popcll(lo) + __popcll(hi);
}

// --- kernel B: conv (blocks 0..1023) || pos (blocks 1024..5119) ---
// Independent halves overlap in one launch (r18-verified code, fence-free).
__global__ __launch_bounds__(256) void convpos_kernel(const float* __restrict__ f,
                                                      unsigned short* __restrict__ ctr,
                                                      const ulonglong2* __restrict__ bits,
                                                      const int* __restrict__ scnt,
                                                      unsigned long long* __restrict__ posw,
                                                      int* __restrict__ poscnt){
  int bid = blockIdx.x;
  int tid = threadIdx.x;
  if (bid < 1024){
    int t = bid * 256 + tid;                   // 0..262143, one 16B unit each
    int l  = t & 63;
    int fg = t >> 9;                           // fragment group 0..511
    int cg = (t >> 6) & 7;                     // chunk group 0..7
    int j  = l >> 4;                           // chunk-in-group 0..3
    int r  = l & 15;                           // row-in-group 0..15
    int row = (fg << 4) + r;                   // 0..8191
    int c   = (cg << 2) + j;                   // 16B chunk 0..31
    int v = row >> 12, b = row & 4095;
    const float* src = f + ((((size_t)b << 1) + v) << 8) + (c << 3);
    float4 a = *(const float4*)src;
    float4 cc = *(const float4*)(src + 4);
    uint4 o;
    o.x = (unsigned)f2bf(a.x)  | ((unsigned)f2bf(a.y)  << 16);
    o.y = (unsigned)f2bf(a.z)  | ((unsigned)f2bf(a.w)  << 16);
    o.z = (unsigned)f2bf(cc.x) | ((unsigned)f2bf(cc.y) << 16);
    o.w = (unsigned)f2bf(cc.z) | ((unsigned)f2bf(cc.w) << 16);
    *(uint4*)((char*)ctr + ((size_t)t << 4)) = o;
  } else {
    __shared__ unsigned long long rbl[16], rbh[16];
    __shared__ int rs_sh[16];
    int pb = bid - 1024;                       // 0..4095
    int i0 = (pb >> 4) << 4;                   // row group base
    int jm = ((pb & 15) << 8) + tid;           // this thread's column
    if (tid < 16){
      ulonglong2 bb = bits[i0 + tid];
      rbl[tid] = bb.x; rbh[tid] = bb.y;
      rs_sh[tid] = scnt[i0 + tid];
    }
    __syncthreads();
    ulonglong2 bj = bits[jm];
    int sj = scnt[jm];
    int lane = tid & 63;
    int wword = ((pb & 15) << 2) + (tid >> 6); // jm >> 6
    #pragma unroll
    for (int r = 0; r < 16; ++r){
      int inter = __popcll(rbl[r] & bj.x) + __popcll(rbh[r] & bj.y);
      int uni = rs_sh[r] + sj - inter;
      bool hit = false;
      if (2 * inter >= uni){                   // integer prefilter (superset)
        float sim = (float)inter / ((float)uni + 1e-6f);
        hit = (sim >= 0.5f);
      }
      unsigned long long m = __ballot(hit);
      if (lane == 0){
        posw[(size_t)(i0 + r) * 64 + wword] = m;
        if (m) atomicAdd(&poscnt[i0 + r], __popcll(m));
      }
    }
  }
}

// ---- kernel C: fused GEMM, fragment-major, symmetry-halved (r16-EXACT) ----
#define GLDS16(g, l) __builtin_amdgcn_global_load_lds( \
    (const __attribute__((address_space(1))) unsigned int*)(unsigned long long)(uintptr_t)(g), \
    (__attribute__((address_space(3))) unsigned int*)(unsigned int)(uintptr_t)(l), 16, 0, 0)

__global__ __launch_bounds__(256) void gemm_kernel(const unsigned short* __restrict__ ctr,
                                                   const unsigned long long* __restrict__ posw,
                                                   float* __restrict__ total,
                                                   float* __restrict__ possum){
  __shared__ __align__(16) char Bl[32768];     // 4 col-groups x 8KB, fm order
  const int tid  = threadIdx.x;
  const int lane = tid & 63;
  const int w    = tid >> 6;                   // 0..3
  const int lr   = lane & 15, lk = lane >> 4;
  const int bid = (int)blockIdx.x;

  int rb, cb;
  bool doCol;
  if (bid < 1024){
    const int swz = (bid & 7) * 128 + (bid >> 3);
    rb = swz & 31; cb = 32 + (swz >> 5);
    doCol = false;
  } else {
    int t0 = bid - 1024;                       // 0..527
    int t  = (t0 & 7) * 66 + (t0 >> 3);
    int r = (int)((65.0f - sqrtf((float)(4225 - 8 * t))) * 0.5f);
    while ((r + 1) * (65 - (r + 1)) / 2 <= t) ++r;
    while (r * (65 - r) / 2 > t) --r;
    rb = r;
    cb = r + (t - r * (65 - r) / 2);
    doCol = (rb != cb);
  }
  const int i0 = rb << 7, n0 = cb << 7;
  const char* ctrB = (const char*)ctr;

  #define STAGEH(H) do { \
    const char* src_ = ctrB + ((size_t)((n0 >> 4) + ((H) << 2)) << 13); \
    _Pragma("unroll") \
    for (int is = 0; is < 8; ++is){ \
      int off_ = (is << 12) + (w << 10);       /* wave-uniform */ \
      GLDS16(src_ + off_ + (lane << 4), Bl + off_); \
    } } while(0)

  // ---- A fragments: contiguous 1KB per wave-load (fragment-major)
  bf16x8 a[2][8];
  #pragma unroll
  for (int rt = 0; rt < 2; ++rt){
    const char* gbase = ctrB + ((size_t)((i0 >> 4) + (w << 1) + rt) << 13);
    #pragma unroll
    for (int ks = 0; ks < 8; ++ks)
      a[rt][ks] = *(const bf16x8*)(gbase + (ks << 10) + (lane << 4));
  }

  const int rowb = i0 + (w << 5) + (lk << 2);  // + rt*16 + q = this lane's rows
  float tot[2][4], pos[2][4];
  #pragma unroll
  for (int rt = 0; rt < 2; ++rt)
    #pragma unroll
    for (int q = 0; q < 4; ++q){ tot[rt][q] = 0.f; pos[rt][q] = 0.f; }

  STAGEH(0);
  __syncthreads();
  #pragma unroll
  for (int h = 0; h < 2; ++h){
    if (h){
      __syncthreads();                         // all reads of half0 done
      STAGEH(1);
      __syncthreads();
    }
    const int widx = ((n0 & 4095) >> 6) + h;
    unsigned pbits = 0;
    #pragma unroll
    for (int rt = 0; rt < 2; ++rt)
      #pragma unroll
      for (int q = 0; q < 4; ++q){
        unsigned long long wv = posw[(size_t)(rowb + (rt << 4) + q) * 64 + widx];
        unsigned m4 = (unsigned)((wv >> lr) & 1ull)
                    | ((unsigned)((wv >> (16 + lr)) & 1ull) << 1)
                    | ((unsigned)((wv >> (32 + lr)) & 1ull) << 2)
                    | ((unsigned)((wv >> (48 + lr)) & 1ull) << 3);
        pbits |= m4 << (((rt << 2) + q) << 2);
      }

    #pragma unroll
    for (int ng = 0; ng < 4; ++ng){
      const char* bbase = Bl + (ng << 13);     // 8KB per col-group
      f32x4 acc0 = {0.f, 0.f, 0.f, 0.f};
      f32x4 acc1 = {0.f, 0.f, 0.f, 0.f};
      #pragma unroll
      for (int ks = 0; ks < 8; ++ks){
        bf16x8 b = *(const bf16x8*)(bbase + (ks << 10) + (lane << 4));
        acc0 = __builtin_amdgcn_mfma_f32_16x16x32_bf16(a[0][ks], b, acc0, 0, 0, 0);
        acc1 = __builtin_amdgcn_mfma_f32_16x16x32_bf16(a[1][ks], b, acc1, 0, 0, 0);
      }
      const int gcol = n0 + (h << 6) + (ng << 4) + lr;
      float ct = 0.f, cp = 0.f;                // column partials (this lane)
      #pragma unroll
      for (int q = 0; q < 4; ++q){
        float e0 = fast_exp2(acc0[q] * EXP2SC);
        e0 = ((rowb + q) == gcol) ? 0.f : e0;
        tot[0][q] += e0;
        bool b0 = (pbits >> ((q << 2) + ng)) & 1u;
        if (b0) pos[0][q] += e0;
        float e1 = fast_exp2(acc1[q] * EXP2SC);
        e1 = ((rowb + 16 + q) == gcol) ? 0.f : e1;
        tot[1][q] += e1;
        bool b1 = (pbits >> (((4 + q) << 2) + ng)) & 1u;
        if (b1) pos[1][q] += e1;
        if (doCol){
          ct += e0 + e1;
          cp += (b0 ? e0 : 0.f) + (b1 ? e1 : 0.f);
        }
      }
      if (doCol){
        ct += __shfl_xor(ct, 16); cp += __shfl_xor(cp, 16);
        ct += __shfl_xor(ct, 32); cp += __shfl_xor(cp, 32);
        if (lk == 0){                          // one lane per column per wave
          atomicAdd(&total[gcol], ct);
          if (cp != 0.f) atomicAdd(&possum[gcol], cp);
        }
      }
    }
  }

  // ---- reduce across lr (16 lanes) and one atomic pair per row ----
  #pragma unroll
  for (int rt = 0; rt < 2; ++rt){
    #pragma unroll
    for (int q = 0; q < 4; ++q){
      float v = tot[rt][q], u = pos[rt][q];
      v += __shfl_xor(v, 1); u += __shfl_xor(u, 1);
      v += __shfl_xor(v, 2); u += __shfl_xor(u, 2);
      v += __shfl_xor(v, 4); u += __shfl_xor(u, 4);
      v += __shfl_xor(v, 8); u += __shfl_xor(u, 8);
      if (lr == 0){
        int grow = rowb + (rt << 4) + q;
        atomicAdd(&total[grow], v);
        if (u != 0.f) atomicAdd(&possum[grow], u);
      }
    }
  }
  #undef STAGEH
}

// ---------------- kernel D: finalize loss (r16-verified) ----------------
__global__ __launch_bounds__(1024) void fin_kernel(const float* __restrict__ possum,
                                                   const float* __restrict__ total,
                                                   const int* __restrict__ poscnt,
                                                   const int* __restrict__ scnt,
                                                   float* __restrict__ out){
  int tid = threadIdx.x;
  float ls = 0.f, hc = 0.f;
  #pragma unroll
  for (int k = 0; k < 4; ++k){
    int i = k * 1024 + tid;
    int pii = (scnt[i] > 0) ? 1 : 0;
    int pm = 2 * poscnt[i] - pii;        // pos_m row count (self col removed)
    if (pm > 0){
      float ps = possum[i];
      float neg = total[i] - ps;
      ls += logf((ps + neg + 1e-8f) / ps);
      hc += 1.f;
    }
  }
  ls += __shfl_xor(ls, 1);  ls += __shfl_xor(ls, 2);  ls += __shfl_xor(ls, 4);
  ls += __shfl_xor(ls, 8);  ls += __shfl_xor(ls, 16); ls += __shfl_xor(ls, 32);
  hc += __shfl_xor(hc, 1);  hc += __shfl_xor(hc, 2);  hc += __shfl_xor(hc, 4);
  hc += __shfl_xor(hc, 8);  hc += __shfl_xor(hc, 16); hc += __shfl_xor(hc, 32);
  __shared__ float sl[16], sh[16];
  if ((tid & 63) == 0){ sl[tid >> 6] = ls; sh[tid >> 6] = hc; }
  __syncthreads();
  if (tid == 0){
    float S = 0.f, H = 0.f;
    #pragma unroll
    for (int w2 = 0; w2 < 16; ++w2){ S += sl[w2]; H += sh[w2]; }
    out[0] = S / fmaxf(H, 1.f);
  }
}

extern "C" void kernel_launch(void* const* d_in, const int* in_sizes, int n_in,
                              void* d_out, int out_size, void* d_ws, size_t ws_size,
                              hipStream_t stream){
  (void)in_sizes; (void)n_in; (void)out_size; (void)ws_size;
  const float* feat   = (const float*)d_in[0];
  const float* labels = (const float*)d_in[1];
  float* out = (float*)d_out;
  char* ws = (char*)d_ws;
  unsigned short* ctr       = (unsigned short*)(ws);               // 4,194,304 B
  unsigned long long* posw  = (unsigned long long*)(ws + 4194304); // 2,097,152 B
  ulonglong2* bits          = (ulonglong2*)(ws + 6291456);         //    65,536 B
  int* scnt                 = (int*)(ws + 6356992);                //    16,384 B
  float* possum             = (float*)(ws + 6373376);              //    16,384 B
  float* total              = (float*)(ws + 6389760);              //    16,384 B
  int* poscnt               = (int*)(ws + 6406144);                //    16,384 B

  hipLaunchKernelGGL(pack_kernel,    dim3(16),   dim3(256),  0, stream, labels, bits, scnt, possum, total, poscnt);
  hipLaunchKernelGGL(convpos_kernel, dim3(5120), dim3(256),  0, stream, feat, ctr, bits, scnt, posw, poscnt);
  hipLaunchKernelGGL(gemm_kernel,    dim3(1552), dim3(256),  0, stream, ctr, posw, total, possum);
  hipLaunchKernelGGL(fin_kernel,     dim3(1),    dim3(1024), 0, stream, possum, total, poscnt, scnt, out);
}

// Round 20
// 58.151 us; speedup vs baseline: 2.6867x; 1.0257x over previous
//
#include <hip/hip_runtime.h>

#define B_ 4096
#define D_ 256
#define N_ 8192
// log2(e)/0.07
#define EXP2SC 20.60992915555662f

typedef float f32x4 __attribute__((ext_vector_type(4)));
typedef __bf16 bf16x8 __attribute__((ext_vector_type(8)));

__device__ __forceinline__ float fast_exp2(float x){
#if __has_builtin(__builtin_amdgcn_exp2f)
  return __builtin_amdgcn_exp2f(x);
#else
  return exp2f(x);
#endif
}

__device__ __forceinline__ unsigned short f2bf(float x){
  unsigned int u = __float_as_uint(x);
  unsigned int r = (u + 0x7fffu + ((u >> 16) & 1u)) >> 16;
  return (unsigned short)r;
}

// --- kernel 1: merged prep = pack labels + zero accums (blocks 0..15)
//     and f32->bf16 fragment-major convert (blocks 16..1039) --- (r16-exact)
__global__ __launch_bounds__(256) void prep_kernel(const float* __restrict__ labels,
                                                   const float* __restrict__ f,
                                                   ulonglong2* __restrict__ bits,
                                                   int* __restrict__ scnt,
                                                   unsigned short* __restrict__ ctr,
                                                   float* __restrict__ possum,
                                                   float* __restrict__ total,
                                                   int* __restrict__ poscnt){
  int bid = blockIdx.x;
  int tid = threadIdx.x;
  if (bid < 16){
    int i = bid * 256 + tid;                   // 0..4095
    possum[i] = 0.f; total[i] = 0.f; poscnt[i] = 0;
    const float* L = labels + (size_t)i * 80;
    unsigned long long lo = 0ull, hi = 0ull;
    #pragma unroll
    for (int c = 0; c < 64; ++c) lo |= (L[c] > 0.5f) ? (1ull << c) : 0ull;
    #pragma unroll
    for (int c = 64; c < 80; ++c) hi |= (L[c] > 0.5f) ? (1ull << (c - 64)) : 0ull;
    bits[i] = make_ulonglong2(lo, hi);
    scnt[i] = __popcll(lo) + __popcll(hi);
  } else {
    int t = (bid - 16) * 256 + tid;            // 0..262143, 8 elems each
    int row = t >> 5;                          // 0..8191
    int c   = t & 31;                          // 16B chunk 0..31
    int v = row >> 12, b = row & 4095;
    const float* src = f + ((((size_t)b << 1) + v) << 8) + (c << 3);
    float4 a = *(const float4*)src;
    float4 cc = *(const float4*)(src + 4);
    uint4 o;
    o.x = (unsigned)f2bf(a.x)  | ((unsigned)f2bf(a.y)  << 16);
    o.y = (unsigned)f2bf(a.z)  | ((unsigned)f2bf(a.w)  << 16);
    o.z = (unsigned)f2bf(cc.x) | ((unsigned)f2bf(cc.y) << 16);
    o.w = (unsigned)f2bf(cc.z) | ((unsigned)f2bf(cc.w) << 16);
    size_t oaddr = ((size_t)(row >> 4) << 13) + ((size_t)(c >> 2) << 10)
                 + ((size_t)(c & 3) << 8) + ((size_t)(row & 15) << 4);
    *(uint4*)((char*)ctr + oaddr) = o;
  }
}

// ------ kernel 2: Jaccard pos bitmask + fused per-row popcount ------
__global__ __launch_bounds__(256) void pos_kernel(const ulonglong2* __restrict__ bits,
                                                  const int* __restrict__ scnt,
                                                  unsigned long long* __restrict__ posw,
                                                  int* __restrict__ poscnt){
  __shared__ unsigned long long rbl[16], rbh[16];
  __shared__ int rs_sh[16];
  int tid = threadIdx.x;
  int bid = blockIdx.x;
  int i0 = (bid >> 4) << 4;                   // row group base
  int jm = ((bid & 15) << 8) + tid;           // this thread's column
  if (tid < 16){
    ulonglong2 bb = bits[i0 + tid];
    rbl[tid] = bb.x; rbh[tid] = bb.y;
    rs_sh[tid] = scnt[i0 + tid];
  }
  __syncthreads();
  ulonglong2 bj = bits[jm];
  int sj = scnt[jm];
  int lane = tid & 63;
  int wword = ((bid & 15) << 2) + (tid >> 6); // jm >> 6
  #pragma unroll
  for (int r = 0; r < 16; ++r){
    int inter = __popcll(rbl[r] & bj.x) + __popcll(rbh[r] & bj.y);
    int uni = rs_sh[r] + sj - inter;
    bool hit = false;
    if (2 * inter >= uni){                     // integer prefilter (superset)
      float sim = (float)inter / ((float)uni + 1e-6f);
      hit = (sim >= 0.5f);
    }
    unsigned long long m = __ballot(hit);
    if (lane == 0){
      posw[(size_t)(i0 + r) * 64 + wword] = m;
      if (m) atomicAdd(&poscnt[i0 + r], __popcll(m));  // sparse: ~2-3 hits/row
    }
  }
}

// ---- kernel 3: fused GEMM, fragment-major, SYMMETRY-HALVED left block ----
// (r16-exact) grid 1552 = 1024 right-half tiles + 528 left-triangle tiles;
// off-diagonal triangle tiles contribute row AND column sums.
#define GLDS16(g, l) __builtin_amdgcn_global_load_lds( \
    (const __attribute__((address_space(1))) unsigned int*)(unsigned long long)(uintptr_t)(g), \
    (__attribute__((address_space(3))) unsigned int*)(unsigned int)(uintptr_t)(l), 16, 0, 0)

__global__ __launch_bounds__(256) void gemm_kernel(const unsigned short* __restrict__ ctr,
                                                   const unsigned long long* __restrict__ posw,
                                                   float* __restrict__ total,
                                                   float* __restrict__ possum){
  __shared__ __align__(16) char Bl[32768];     // 4 col-groups x 8KB, fm order
  const int tid  = threadIdx.x;
  const int lane = tid & 63;
  const int w    = tid >> 6;                   // 0..3
  const int lr   = lane & 15, lk = lane >> 4;
  const int bid = (int)blockIdx.x;

  int rb, cb;
  bool doCol;
  if (bid < 1024){
    // right half: cols 4096..8191, bijective XCD swizzle
    const int swz = (bid & 7) * 128 + (bid >> 3);
    rb = swz & 31; cb = 32 + (swz >> 5);
    doCol = false;
  } else {
    // left triangle: rb <= cb < 32; 528 = 8 x 66 bijective interleave
    int t0 = bid - 1024;                       // 0..527
    int t  = (t0 & 7) * 66 + (t0 >> 3);
    int r = (int)((65.0f - sqrtf((float)(4225 - 8 * t))) * 0.5f);
    while ((r + 1) * (65 - (r + 1)) / 2 <= t) ++r;
    while (r * (65 - r) / 2 > t) --r;
    rb = r;
    cb = r + (t - r * (65 - r) / 2);
    doCol = (rb != cb);
  }
  const int i0 = rb << 7, n0 = cb << 7;
  const char* ctrB = (const char*)ctr;

  #define STAGEH(H) do { \
    const char* src_ = ctrB + ((size_t)((n0 >> 4) + ((H) << 2)) << 13); \
    _Pragma("unroll") \
    for (int is = 0; is < 8; ++is){ \
      int off_ = (is << 12) + (w << 10);       /* wave-uniform */ \
      GLDS16(src_ + off_ + (lane << 4), Bl + off_); \
    } } while(0)

  // ---- A fragments: contiguous 1KB per wave-load (fragment-major)
  bf16x8 a[2][8];
  #pragma unroll
  for (int rt = 0; rt < 2; ++rt){
    const char* gbase = ctrB + ((size_t)((i0 >> 4) + (w << 1) + rt) << 13);
    #pragma unroll
    for (int ks = 0; ks < 8; ++ks)
      a[rt][ks] = *(const bf16x8*)(gbase + (ks << 10) + (lane << 4));
  }

  const int rowb = i0 + (w << 5) + (lk << 2);  // + rt*16 + q = this lane's rows
  float tot[2][4], pos[2][4];
  #pragma unroll
  for (int rt = 0; rt < 2; ++rt)
    #pragma unroll
    for (int q = 0; q < 4; ++q){ tot[rt][q] = 0.f; pos[rt][q] = 0.f; }

  STAGEH(0);
  __syncthreads();
  #pragma unroll
  for (int h = 0; h < 2; ++h){
    if (h){
      __syncthreads();                         // all reads of half0 done
      STAGEH(1);
      __syncthreads();
    }
    // pos bits for this 64-col half (r6/r11-verified packing)
    const int widx = ((n0 & 4095) >> 6) + h;
    unsigned pbits = 0;
    #pragma unroll
    for (int rt = 0; rt < 2; ++rt)
      #pragma unroll
      for (int q = 0; q < 4; ++q){
        unsigned long long wv = posw[(size_t)(rowb + (rt << 4) + q) * 64 + widx];
        unsigned m4 = (unsigned)((wv >> lr) & 1ull)
                    | ((unsigned)((wv >> (16 + lr)) & 1ull) << 1)
                    | ((unsigned)((wv >> (32 + lr)) & 1ull) << 2)
                    | ((unsigned)((wv >> (48 + lr)) & 1ull) << 3);
        pbits |= m4 << (((rt << 2) + q) << 2);
      }

    #pragma unroll
    for (int ng = 0; ng < 4; ++ng){
      const char* bbase = Bl + (ng << 13);     // 8KB per col-group
      f32x4 acc0 = {0.f, 0.f, 0.f, 0.f};
      f32x4 acc1 = {0.f, 0.f, 0.f, 0.f};
      #pragma unroll
      for (int ks = 0; ks < 8; ++ks){
        bf16x8 b = *(const bf16x8*)(bbase + (ks << 10) + (lane << 4));
        acc0 = __builtin_amdgcn_mfma_f32_16x16x32_bf16(a[0][ks], b, acc0, 0, 0, 0);
        acc1 = __builtin_amdgcn_mfma_f32_16x16x32_bf16(a[1][ks], b, acc1, 0, 0, 0);
      }
      const int gcol = n0 + (h << 6) + (ng << 4) + lr;
      float ct = 0.f, cp = 0.f;                // column partials (this lane)
      #pragma unroll
      for (int q = 0; q < 4; ++q){
        float e0 = fast_exp2(acc0[q] * EXP2SC);
        e0 = ((rowb + q) == gcol) ? 0.f : e0;
        tot[0][q] += e0;
        bool b0 = (pbits >> ((q << 2) + ng)) & 1u;
        if (b0) pos[0][q] += e0;
        float e1 = fast_exp2(acc1[q] * EXP2SC);
        e1 = ((rowb + 16 + q) == gcol) ? 0.f : e1;
        tot[1][q] += e1;
        bool b1 = (pbits >> (((4 + q) << 2) + ng)) & 1u;
        if (b1) pos[1][q] += e1;
        if (doCol){
          ct += e0 + e1;
          cp += (b0 ? e0 : 0.f) + (b1 ? e1 : 0.f);
        }
      }
      if (doCol){
        ct += __shfl_xor(ct, 16); cp += __shfl_xor(cp, 16);
        ct += __shfl_xor(ct, 32); cp += __shfl_xor(cp, 32);
        if (lk == 0){                          // one lane per column per wave
          atomicAdd(&total[gcol], ct);
          if (cp != 0.f) atomicAdd(&possum[gcol], cp);
        }
      }
    }
  }

  // ---- reduce across lr (16 lanes) and one atomic pair per row ----
  #pragma unroll
  for (int rt = 0; rt < 2; ++rt){
    #pragma unroll
    for (int q = 0; q < 4; ++q){
      float v = tot[rt][q], u = pos[rt][q];
      v += __shfl_xor(v, 1); u += __shfl_xor(u, 1);
      v += __shfl_xor(v, 2); u += __shfl_xor(u, 2);
      v += __shfl_xor(v, 4); u += __shfl_xor(u, 4);
      v += __shfl_xor(v, 8); u += __shfl_xor(u, 8);
      if (lr == 0){
        int grow = rowb + (rt << 4) + q;
        atomicAdd(&total[grow], v);
        if (u != 0.f) atomicAdd(&possum[grow], u);
      }
    }
  }
  #undef STAGEH
}

// ---------------- kernel 4: finalize loss ----------------
__global__ __launch_bounds__(1024) void fin_kernel(const float* __restrict__ possum,
                                                   const float* __restrict__ total,
                                                   const int* __restrict__ poscnt,
                                                   const int* __restrict__ scnt,
                                                   float* __restrict__ out){
  int tid = threadIdx.x;
  float ls = 0.f, hc = 0.f;
  #pragma unroll
  for (int k = 0; k < 4; ++k){
    int i = k * 1024 + tid;
    int pii = (scnt[i] > 0) ? 1 : 0;
    int pm = 2 * poscnt[i] - pii;        // pos_m row count (self col removed)
    if (pm > 0){
      float ps = possum[i];
      float neg = total[i] - ps;
      ls += logf((ps + neg + 1e-8f) / ps);
      hc += 1.f;
    }
  }
  ls += __shfl_xor(ls, 1);  ls += __shfl_xor(ls, 2);  ls += __shfl_xor(ls, 4);
  ls += __shfl_xor(ls, 8);  ls += __shfl_xor(ls, 16); ls += __shfl_xor(ls, 32);
  hc += __shfl_xor(hc, 1);  hc += __shfl_xor(hc, 2);  hc += __shfl_xor(hc, 4);
  hc += __shfl_xor(hc, 8);  hc += __shfl_xor(hc, 16); hc += __shfl_xor(hc, 32);
  __shared__ float sl[16], sh[16];
  if ((tid & 63) == 0){ sl[tid >> 6] = ls; sh[tid >> 6] = hc; }
  __syncthreads();
  if (tid == 0){
    float S = 0.f, H = 0.f;
    #pragma unroll
    for (int w2 = 0; w2 < 16; ++w2){ S += sl[w2]; H += sh[w2]; }
    out[0] = S / fmaxf(H, 1.f);
  }
}

extern "C" void kernel_launch(void* const* d_in, const int* in_sizes, int n_in,
                              void* d_out, int out_size, void* d_ws, size_t ws_size,
                              hipStream_t stream){
  (void)in_sizes; (void)n_in; (void)out_size; (void)ws_size;
  const float* feat   = (const float*)d_in[0];
  const float* labels = (const float*)d_in[1];
  float* out = (float*)d_out;
  char* ws = (char*)d_ws;
  unsigned short* ctr       = (unsigned short*)(ws);               // 4,194,304 B
  unsigned long long* posw  = (unsigned long long*)(ws + 4194304); // 2,097,152 B
  ulonglong2* bits          = (ulonglong2*)(ws + 6291456);         //    65,536 B
  int* scnt                 = (int*)(ws + 6356992);                //    16,384 B
  float* possum             = (float*)(ws + 6373376);              //    16,384 B
  float* total              = (float*)(ws + 6389760);              //    16,384 B
  int* poscnt               = (int*)(ws + 6406144);                //    16,384 B

  hipLaunchKernelGGL(prep_kernel, dim3(1040), dim3(256),  0, stream, labels, feat, bits, scnt, ctr, possum, total, poscnt);
  hipLaunchKernelGGL(pos_kernel,  dim3(4096), dim3(256),  0, stream, bits, scnt, posw, poscnt);
  hipLaunchKernelGGL(gemm_kernel, dim3(1552), dim3(256),  0, stream, ctr, posw, total, possum);
  hipLaunchKernelGGL(fin_kernel,  dim3(1),    dim3(1024), 0, stream, possum, total, poscnt, scnt, out);
}